// Round 5
// baseline (687.498 us; speedup 1.0000x reference)
//
#include <hip/hip_runtime.h>
#include <hip/hip_bf16.h>
#include <math.h>

#define BDIM 1024
typedef __hip_bfloat16 bf16;

// Device buffers confirmed float32.

__device__ __forceinline__ float sigm(float v)  { return 1.0f / (1.0f + __expf(-v)); }
// tanh via hardware exp: exact at saturation, ~1e-6 abs err elsewhere.
__device__ __forceinline__ float ftanh(float v) { return 1.0f - 2.0f / (__expf(2.0f * v) + 1.0f); }
__device__ __forceinline__ float mod360(float v){ return v - 360.0f * floorf(v * (1.0f / 360.0f)); }

// atan2 in degrees (slow path only; result feeds 30-deg bins).
__device__ __forceinline__ float atan2_deg(float y, float x) {
  float ax = fabsf(x), ay = fabsf(y);
  float mx = fmaxf(ax, ay), mn = fminf(ax, ay);
  float r = mn / fmaxf(mx, 1e-30f);
  float r2 = r * r;
  float a = r * (0.99997726f + r2 * (-0.33262347f + r2 * (0.19354346f +
            r2 * (-0.11643287f + r2 * (0.05265332f - r2 * 0.01172120f)))));
  if (ay > ax) a = 1.5707963267948966f - a;
  if (x < 0.0f) a = 3.141592653589793f - a;
  a = copysignf(a, y);
  return a * 57.29577951308232f;
}

union EUCtx {
  float E[64][16];    // embedding (live: step start -> LSTM)
  float Ctx[64][33];  // temporal context (live: temporal -> wtemp)
};

struct Smem {
  alignas(16) float H[64][32];     // carry h
  alignas(16) float C[64][32];     // carry c
  float HC[64][33];                // lstm output (pad 33)
  alignas(16) float Emb[64][32];   // decoder spatial output
  alignas(16) EUCtx u;
  float Enc[8][2120];              // [t][p*33+k]
  alignas(16) float W[64][68];     // spatial weights (stride 68: float4-aligned)
  float RS[64];                    // 1/(rowsum+1e-8)
  bf16  WtT[64][32];               // W_temp^T, bf16
  alignas(16) float WL[128][52];   // LSTM weights [j][ih(16)|hh(32)|pad]
  float Wemb[16][2];
  float Bemb[16];
  float BsumE[128], BsumD[128];
  float Dom[144];
  float Btemp[32];
  float Wout[2][32];
  float Bout[2];
  float Mask[64];
  float Pos[64][2];                // slow path only
  float Head[64];                  // slow path only
  float Xprev[64][2];
  float Xout[64][2];
  float MV[4];
};
static_assert(sizeof(Smem) <= 160 * 1024, "LDS over budget");

__device__ __forceinline__ void stage_wl(int tid, Smem& s,
    const float* __restrict__ Wih, const float* __restrict__ Whh) {
  for (int idx = tid; idx < 128 * 48; idx += BDIM) {
    int j = idx / 48, m = idx - j * 48;
    s.WL[j][m] = (m < 16) ? Wih[j * 16 + m] : Whh[j * 32 + (m - 16)];
  }
}

// LSTM: thread (k=tid&31, pg=tid>>5) -> 4 gates x 2 pedestrians.
__device__ __forceinline__ void lstm_stream(int tid, Smem& s,
    const float (*Hin)[32], const float* __restrict__ bsum) {
  const int k = tid & 31, pg = tid >> 5, p0 = pg * 2;
  const float4* W0 = (const float4*)s.WL[k];
  const float4* W1 = (const float4*)s.WL[32 + k];
  const float4* W2 = (const float4*)s.WL[64 + k];
  const float4* W3 = (const float4*)s.WL[96 + k];
  float a0[2], a1[2], a2[2], a3[2];
  {
    const float b0 = bsum[k], b1 = bsum[32 + k], b2 = bsum[64 + k], b3 = bsum[96 + k];
    #pragma unroll
    for (int pi = 0; pi < 2; ++pi) { a0[pi] = b0; a1[pi] = b1; a2[pi] = b2; a3[pi] = b3; }
  }
  #pragma unroll
  for (int m4 = 0; m4 < 4; ++m4) {           // embedding part
    float4 w0 = W0[m4], w1 = W1[m4], w2 = W2[m4], w3 = W3[m4];
    #pragma unroll
    for (int pi = 0; pi < 2; ++pi) {
      float4 xv = ((const float4*)s.u.E[p0 + pi])[m4];
      a0[pi] += xv.x * w0.x + xv.y * w0.y + xv.z * w0.z + xv.w * w0.w;
      a1[pi] += xv.x * w1.x + xv.y * w1.y + xv.z * w1.z + xv.w * w1.w;
      a2[pi] += xv.x * w2.x + xv.y * w2.y + xv.z * w2.z + xv.w * w2.w;
      a3[pi] += xv.x * w3.x + xv.y * w3.y + xv.z * w3.z + xv.w * w3.w;
    }
  }
  #pragma unroll
  for (int m4 = 0; m4 < 8; ++m4) {           // hidden part
    float4 w0 = W0[4 + m4], w1 = W1[4 + m4], w2 = W2[4 + m4], w3 = W3[4 + m4];
    #pragma unroll
    for (int pi = 0; pi < 2; ++pi) {
      float4 hv = ((const float4*)Hin[p0 + pi])[m4];
      a0[pi] += hv.x * w0.x + hv.y * w0.y + hv.z * w0.z + hv.w * w0.w;
      a1[pi] += hv.x * w1.x + hv.y * w1.y + hv.z * w1.z + hv.w * w1.w;
      a2[pi] += hv.x * w2.x + hv.y * w2.y + hv.z * w2.z + hv.w * w2.w;
      a3[pi] += hv.x * w3.x + hv.y * w3.y + hv.z * w3.z + hv.w * w3.w;
    }
  }
  #pragma unroll
  for (int pi = 0; pi < 2; ++pi) {
    const int p = p0 + pi;
    float iv = sigm(a0[pi]), fv = sigm(a1[pi]);
    float gv = ftanh(a2[pi]), ov = sigm(a3[pi]);
    float cn = fv * s.C[p][k] + iv * gv;
    s.C[p][k] = cn;
    s.HC[p][k] = ov * ftanh(cn);
  }
}

__global__ __launch_bounds__(BDIM, 1) void traj_fwd(
    const float* __restrict__ gx, const float* __restrict__ gdmat,
    const float* __restrict__ gbmat, const float* __restrict__ ghmat,
    const float* __restrict__ gimask,
    const float* __restrict__ gmean, const float* __restrict__ gvar,
    const float* __restrict__ gWemb, const float* __restrict__ gbemb,
    const float* __restrict__ gWihE, const float* __restrict__ gWhhE,
    const float* __restrict__ gbihE, const float* __restrict__ gbhhE,
    const float* __restrict__ gWihD, const float* __restrict__ gWhhD,
    const float* __restrict__ gbihD, const float* __restrict__ gbhhD,
    const float* __restrict__ gdom, const float* __restrict__ gWtemp,
    const float* __restrict__ gbtemp, const float* __restrict__ gWout,
    const float* __restrict__ gbout, float* __restrict__ gout)
{
  __shared__ Smem s;
  const int b = blockIdx.x, tid = threadIdx.x;

  // ---- stage constants; zero state; stage encoder LSTM weights ----
  for (int i = tid; i < 128; i += BDIM) {
    s.BsumE[i] = gbihE[i] + gbhhE[i];
    s.BsumD[i] = gbihD[i] + gbhhD[i];
  }
  for (int i = tid; i < 2048; i += BDIM) {
    int kp = i >> 6, m = i & 63;
    s.WtT[m][kp] = __float2bfloat16(gWtemp[i]);
  }
  for (int i = tid; i < 144; i += BDIM) s.Dom[i] = gdom[i];
  if (tid < 32) s.Btemp[tid] = gbtemp[tid];
  if (tid < 64) s.Wout[tid >> 5][tid & 31] = gWout[tid];
  if (tid < 2)  s.Bout[tid] = gbout[tid];
  if (tid < 16) s.Bemb[tid] = gbemb[tid];
  if (tid < 32) s.Wemb[tid >> 1][tid & 1] = gWemb[tid];
  if (tid < 4)  s.MV[tid] = (tid < 2) ? gmean[b * 2 + tid] : gvar[b * 2 + tid - 2];
  for (int i = tid; i < 2048; i += BDIM) { s.H[i >> 5][i & 31] = 0.0f; s.C[i >> 5][i & 31] = 0.0f; }
  stage_wl(tid, s, gWihE, gWhhE);
  __syncthreads();

  // Uniform-domain fast path detect (exact math shortcut: domain[ih,ib] == Dom[0]).
  bool uni = true;
  {
    const float d0 = s.Dom[0];
    for (int i = 0; i < 144; ++i) uni = uni && (s.Dom[i] == d0);
  }
  const float dom0 = s.Dom[0];

  // ================= ENCODER =================
  for (int t = 0; t < 8; ++t) {
    if (tid < 64) s.Mask[tid] = gimask[(b * 64 + tid) * 8 + t];
    if (tid < 128) {
      int p = tid >> 1, f = tid & 1;
      s.Xprev[p][f] = gx[((b * 64 + p) * 8 + t) * 2 + f];
    }
    __syncthreads();
    {  // W-build (+rowsum via shuffle) and E-build, fused phase
      const int i = tid >> 4, g = tid & 15, j4 = g * 4;
      const float mi = s.Mask[i];
      float w0, w1, w2, w3;
      if (uni) {
        const float4 dv = *(const float4*)&gdmat[(((b * 64 + i) * 8 + t) << 6) + j4];
        w0 = fmaxf(dom0 - dv.x, 0.0f) * mi * s.Mask[j4 + 0];
        w1 = fmaxf(dom0 - dv.y, 0.0f) * mi * s.Mask[j4 + 1];
        w2 = fmaxf(dom0 - dv.z, 0.0f) * mi * s.Mask[j4 + 2];
        w3 = fmaxf(dom0 - dv.w, 0.0f) * mi * s.Mask[j4 + 3];
      } else {
        float wq[4];
        #pragma unroll
        for (int c = 0; c < 4; ++c) {
          int gi = (((b * 64 + i) * 8 + t) << 6) + j4 + c;
          float dv = gdmat[gi], bv = gbmat[gi], hv = ghmat[gi];
          int ibn = (int)floorf(bv * (1.0f / 30.0f)); ibn = ibn < 0 ? 0 : (ibn > 11 ? 11 : ibn);
          int ihn = (int)floorf(hv * (1.0f / 30.0f)); ihn = ihn < 0 ? 0 : (ihn > 11 ? 11 : ihn);
          wq[c] = fmaxf(s.Dom[ihn * 12 + ibn] - dv, 0.0f) * mi * s.Mask[j4 + c];
        }
        w0 = wq[0]; w1 = wq[1]; w2 = wq[2]; w3 = wq[3];
      }
      *(float4*)&s.W[i][j4] = make_float4(w0, w1, w2, w3);
      float tot = w0 + w1 + w2 + w3;
      tot += __shfl_xor(tot, 1); tot += __shfl_xor(tot, 2);
      tot += __shfl_xor(tot, 4); tot += __shfl_xor(tot, 8);
      if (g == 0) s.RS[i] = 1.0f / (tot + 1e-8f);
      // E-build: one element per thread (p=i, k2=g)
      s.u.E[i][g] = s.Xprev[i][0] * s.Wemb[g][0] + s.Xprev[i][1] * s.Wemb[g][1] + s.Bemb[g];
    }
    __syncthreads();
    lstm_stream(tid, s, s.H, s.BsumE);
    __syncthreads();
    {  // spatial attention + tanh -> carry h and Enc[t]
      const int k2 = tid & 31, ig = tid >> 5;
      const int i0 = ig * 2, i1 = i0 + 1;
      float acc0 = 0.0f, acc1 = 0.0f;
      #pragma unroll
      for (int c = 0; c < 16; ++c) {
        float4 wv0 = *(const float4*)&s.W[i0][c * 4];
        float4 wv1 = *(const float4*)&s.W[i1][c * 4];
        float h0 = s.HC[c * 4 + 0][k2], h1 = s.HC[c * 4 + 1][k2];
        float h2 = s.HC[c * 4 + 2][k2], h3 = s.HC[c * 4 + 3][k2];
        acc0 += wv0.x * h0 + wv0.y * h1 + wv0.z * h2 + wv0.w * h3;
        acc1 += wv1.x * h0 + wv1.y * h1 + wv1.z * h2 + wv1.w * h3;
      }
      float v0 = ftanh(acc0 * s.RS[i0]);
      float v1 = ftanh(acc1 * s.RS[i1]);
      s.H[i0][k2] = v0; s.Enc[t][i0 * 33 + k2] = v0;
      s.H[i1][k2] = v1; s.Enc[t][i1 * 33 + k2] = v1;
    }
    __syncthreads();
  }

  // ================= DECODER =================
  stage_wl(tid, s, gWihD, gWhhD);
  for (int i = tid; i < 2048; i += BDIM) s.C[i >> 5][i & 31] = 0.0f;
  if (tid < 128) {
    int p = tid >> 1, f = tid & 1;
    s.Xprev[p][f] = gx[((b * 64 + p) * 8 + 7) * 2 + f];
  }
  if (tid < 64) s.Mask[tid] = gimask[(b * 64 + tid) * 8 + 7];
  __syncthreads();
  // W/RS for decoder step 0 == encoder t=7 (still resident)

  for (int sd = 0; sd < 12; ++sd) {
    {  // phase A: E-build + spatial attn on carry h -> Emb
      const int i = tid >> 4, g = tid & 15;
      s.u.E[i][g] = s.Xprev[i][0] * s.Wemb[g][0] + s.Xprev[i][1] * s.Wemb[g][1] + s.Bemb[g];
      const int k2 = tid & 31, ig = tid >> 5;
      const int i0 = ig * 2, i1 = i0 + 1;
      float acc0 = 0.0f, acc1 = 0.0f;
      #pragma unroll
      for (int c = 0; c < 16; ++c) {
        float4 wv0 = *(const float4*)&s.W[i0][c * 4];
        float4 wv1 = *(const float4*)&s.W[i1][c * 4];
        float h0 = s.H[c * 4 + 0][k2], h1 = s.H[c * 4 + 1][k2];
        float h2 = s.H[c * 4 + 2][k2], h3 = s.H[c * 4 + 3][k2];
        acc0 += wv0.x * h0 + wv0.y * h1 + wv0.z * h2 + wv0.w * h3;
        acc1 += wv1.x * h0 + wv1.y * h1 + wv1.z * h2 + wv1.w * h3;
      }
      s.Emb[i0][k2] = ftanh(acc0 * s.RS[i0]);
      s.Emb[i1][k2] = ftanh(acc1 * s.RS[i1]);
    }
    __syncthreads();
    lstm_stream(tid, s, s.Emb, s.BsumD);
    __syncthreads();
    {  // temporal attention: thread = (p = tid>>4, t = (tid>>1)&7, h = tid&1)
      const int p = tid >> 4, t8 = (tid >> 1) & 7, h = tid & 1;
      const float* hcr = &s.HC[p][h * 16];
      const float* enr = &s.Enc[t8][p * 33 + h * 16];
      float sc = 0.0f;
      #pragma unroll
      for (int kk = 0; kk < 16; ++kk) sc += hcr[kk] * enr[kk];
      sc += __shfl_xor(sc, 1);
      sc *= 0.17677669529663687f;   // 1/sqrt(32)
      float m = gimask[(b * 64 + p) * 8 + t8];
      sc = (m > 0.0f) ? sc : -1e9f;
      float mx = sc;
      mx = fmaxf(mx, __shfl_xor(mx, 2));
      mx = fmaxf(mx, __shfl_xor(mx, 4));
      mx = fmaxf(mx, __shfl_xor(mx, 8));
      float e = __expf(sc - mx);
      float den = e;
      den += __shfl_xor(den, 2);
      den += __shfl_xor(den, 4);
      den += __shfl_xor(den, 8);
      float a = e / den;
      const int kb = t8 * 4 + h * 2;
      float c0 = 0.0f, c1 = 0.0f;
      #pragma unroll
      for (int tt = 0; tt < 8; ++tt) {
        float av = __shfl(a, tt * 2, 16);
        const float* er = &s.Enc[tt][p * 33 + kb];
        c0 += av * er[0]; c1 += av * er[1];
      }
      s.u.Ctx[p][kb] = c0; s.u.Ctx[p][kb + 1] = c1;
    }
    __syncthreads();
    {  // wtemp (+ fused x_out via half-wave shuffle reduce)
      const int kp = tid & 31, pg = tid >> 5;
      float r00, r01, r10, r11;
      #pragma unroll
      for (int pi = 0; pi < 2; ++pi) {
        const int p = pg * 2 + pi;
        float a = s.Btemp[kp];
        #pragma unroll
        for (int m = 0; m < 32; ++m) a += s.u.Ctx[p][m] * __bfloat162float(s.WtT[m][kp]);
        #pragma unroll
        for (int m = 0; m < 32; ++m) a += s.HC[p][m] * __bfloat162float(s.WtT[32 + m][kp]);
        float hv = ftanh(a);
        s.H[p][kp] = hv;
        if (pi == 0) { r00 = hv * s.Wout[0][kp]; r01 = hv * s.Wout[1][kp]; }
        else         { r10 = hv * s.Wout[0][kp]; r11 = hv * s.Wout[1][kp]; }
      }
      #pragma unroll
      for (int st = 1; st < 32; st <<= 1) {
        r00 += __shfl_xor(r00, st); r01 += __shfl_xor(r01, st);
        r10 += __shfl_xor(r10, st); r11 += __shfl_xor(r11, st);
      }
      if (kp == 0) {
        const int p0 = pg * 2;
        float v00 = ftanh(r00 + s.Bout[0]);
        float v01 = ftanh(r01 + s.Bout[1]);
        float v10 = ftanh(r10 + s.Bout[0]);
        float v11 = ftanh(r11 + s.Bout[1]);
        s.Xout[p0][0] = v00; s.Xout[p0][1] = v01;
        s.Xout[p0 + 1][0] = v10; s.Xout[p0 + 1][1] = v11;
        float* go = &gout[((b * 64 + p0) * 12 + sd) * 2];
        go[0] = v00; go[1] = v01; go[24] = v10; go[25] = v11;
      }
    }
    __syncthreads();
    if (sd < 11) {
      if (uni) {
        // fast path: dist depends only on Xout diffs; heading dead.
        const int i = tid >> 4, g = tid & 15, j4 = g * 4;
        const float v0 = s.MV[2], v1 = s.MV[3];
        const float xi0 = s.Xout[i][0], xi1 = s.Xout[i][1];
        const float mi = s.Mask[i];
        float wq[4];
        #pragma unroll
        for (int c = 0; c < 4; ++c) {
          const int j = j4 + c;
          float rx = (s.Xout[j][0] - xi0) * v0;
          float ry = (s.Xout[j][1] - xi1) * v1;
          float dist = sqrtf(rx * rx + ry * ry + 1e-12f);
          wq[c] = fmaxf(dom0 - dist, 0.0f) * mi * s.Mask[j];
        }
        *(float4*)&s.W[i][j4] = make_float4(wq[0], wq[1], wq[2], wq[3]);
        float tot = wq[0] + wq[1] + wq[2] + wq[3];
        tot += __shfl_xor(tot, 1); tot += __shfl_xor(tot, 2);
        tot += __shfl_xor(tot, 4); tot += __shfl_xor(tot, 8);
        if (g == 0) s.RS[i] = 1.0f / (tot + 1e-8f);
        if (tid < 128) { int p = tid >> 1, f = tid & 1; s.Xprev[p][f] = s.Xout[p][f]; }
      } else {
        if (tid < 64) {
          const int p = tid;
          float m0 = s.MV[0], m1 = s.MV[1], v0 = s.MV[2], v1 = s.MV[3];
          float px = s.Xout[p][0] * v0 + m0, py = s.Xout[p][1] * v1 + m1;
          float qx = s.Xprev[p][0] * v0 + m0, qy = s.Xprev[p][1] * v1 + m1;
          s.Head[p] = mod360(atan2_deg(py - qy, px - qx));
          s.Pos[p][0] = px; s.Pos[p][1] = py;
        }
        __syncthreads();
        const int i = tid >> 4, g = tid & 15, j4 = g * 4;
        const float mi = s.Mask[i], hi = s.Head[i];
        const float pix = s.Pos[i][0], piy = s.Pos[i][1];
        float wq[4];
        #pragma unroll
        for (int c = 0; c < 4; ++c) {
          const int j = j4 + c;
          float rx = s.Pos[j][0] - pix;
          float ry = s.Pos[j][1] - piy;
          float dist = sqrtf(rx * rx + ry * ry + 1e-12f);
          float rb = mod360(atan2_deg(ry, rx) - hi);
          float rh = mod360(s.Head[j] - hi);
          int ibn = (int)floorf(rb * (1.0f / 30.0f)); ibn = ibn < 0 ? 0 : (ibn > 11 ? 11 : ibn);
          int ihn = (int)floorf(rh * (1.0f / 30.0f)); ihn = ihn < 0 ? 0 : (ihn > 11 ? 11 : ihn);
          wq[c] = fmaxf(s.Dom[ihn * 12 + ibn] - dist, 0.0f) * mi * s.Mask[j];
        }
        *(float4*)&s.W[i][j4] = make_float4(wq[0], wq[1], wq[2], wq[3]);
        float tot = wq[0] + wq[1] + wq[2] + wq[3];
        tot += __shfl_xor(tot, 1); tot += __shfl_xor(tot, 2);
        tot += __shfl_xor(tot, 4); tot += __shfl_xor(tot, 8);
        if (g == 0) s.RS[i] = 1.0f / (tot + 1e-8f);
        if (tid < 128) { int p = tid >> 1, f = tid & 1; s.Xprev[p][f] = s.Xout[p][f]; }
      }
      __syncthreads();
    }
  }
}

extern "C" void kernel_launch(void* const* d_in, const int* in_sizes, int n_in,
                              void* d_out, int out_size, void* d_ws, size_t ws_size,
                              hipStream_t stream) {
  (void)in_sizes; (void)n_in; (void)d_ws; (void)ws_size; (void)out_size;
  traj_fwd<<<512, BDIM, 0, stream>>>(
      (const float*)d_in[0], (const float*)d_in[1], (const float*)d_in[2],
      (const float*)d_in[3], (const float*)d_in[4],
      /* d_in[5] output_mask, d_in[6] scene unused */
      (const float*)d_in[7], (const float*)d_in[8],
      (const float*)d_in[9], (const float*)d_in[10],
      (const float*)d_in[11], (const float*)d_in[12],
      (const float*)d_in[13], (const float*)d_in[14],
      (const float*)d_in[15], (const float*)d_in[16],
      (const float*)d_in[17], (const float*)d_in[18],
      (const float*)d_in[19], (const float*)d_in[20],
      (const float*)d_in[21], (const float*)d_in[22], (const float*)d_in[23],
      (float*)d_out);
}

// Round 6
// 686.286 us; speedup vs baseline: 1.0018x; 1.0018x over previous
//
#include <hip/hip_runtime.h>
#include <hip/hip_bf16.h>
#include <math.h>

#define BDIM 1024
typedef __hip_bfloat16 bf16;

// Device buffers confirmed float32.

__device__ __forceinline__ float sigm(float v)  { return 1.0f / (1.0f + __expf(-v)); }
// tanh via hardware exp: exact at saturation, ~1e-6 abs err elsewhere.
__device__ __forceinline__ float ftanh(float v) { return 1.0f - 2.0f / (__expf(2.0f * v) + 1.0f); }
__device__ __forceinline__ float mod360(float v){ return v - 360.0f * floorf(v * (1.0f / 360.0f)); }

// atan2 in degrees (slow path only; result feeds 30-deg bins).
__device__ __forceinline__ float atan2_deg(float y, float x) {
  float ax = fabsf(x), ay = fabsf(y);
  float mx = fmaxf(ax, ay), mn = fminf(ax, ay);
  float r = mn / fmaxf(mx, 1e-30f);
  float r2 = r * r;
  float a = r * (0.99997726f + r2 * (-0.33262347f + r2 * (0.19354346f +
            r2 * (-0.11643287f + r2 * (0.05265332f - r2 * 0.01172120f)))));
  if (ay > ax) a = 1.5707963267948966f - a;
  if (x < 0.0f) a = 3.141592653589793f - a;
  a = copysignf(a, y);
  return a * 57.29577951308232f;
}

union EUCtx {
  float E[64][16];    // embedding (live: step start -> LSTM)
  float Ctx[64][33];  // temporal context (live: temporal -> wtemp)
};

struct Smem {
  alignas(16) float H[64][32];     // carry h
  alignas(16) float C[64][32];     // carry c
  float HC[64][33];                // lstm output (pad 33)
  alignas(16) float Emb[64][32];   // decoder spatial output
  alignas(16) EUCtx u;
  float Enc[8][2120];              // [t][p*33+k]
  alignas(16) float W[64][68];     // spatial weights (stride 68: float4-aligned)
  float RS[64];                    // 1/(rowsum+1e-8)
  bf16  WtT[64][32];               // W_temp^T, bf16
  alignas(16) float WL[128][52];   // LSTM weights [j][ih(16)|hh(32)|pad]
  float Wemb[16][2];
  float Bemb[16];
  float BsumE[128], BsumD[128];
  float Dom[144];
  float Btemp[32];
  float Wout[2][32];
  float Bout[2];
  float Mask[64];
  float Pos[64][2];                // slow path only
  float Head[64];                  // slow path only
  float Xprev[64][2];
  float Xout[64][2];
  float MV[4];
};
static_assert(sizeof(Smem) <= 160 * 1024, "LDS over budget");

__device__ __forceinline__ void stage_wl(int tid, Smem& s,
    const float* __restrict__ Wih, const float* __restrict__ Whh) {
  for (int idx = tid; idx < 128 * 48; idx += BDIM) {
    int j = idx / 48, m = idx - j * 48;
    s.WL[j][m] = (m < 16) ? Wih[j * 16 + m] : Whh[j * 32 + (m - 16)];
  }
}

// LSTM: thread (k=tid&31, pg=tid>>5) -> 4 gates x 2 pedestrians.
__device__ __forceinline__ void lstm_stream(int tid, Smem& s,
    const float (*Hin)[32], const float* __restrict__ bsum) {
  const int k = tid & 31, pg = tid >> 5, p0 = pg * 2;
  const float4* W0 = (const float4*)s.WL[k];
  const float4* W1 = (const float4*)s.WL[32 + k];
  const float4* W2 = (const float4*)s.WL[64 + k];
  const float4* W3 = (const float4*)s.WL[96 + k];
  float a0[2], a1[2], a2[2], a3[2];
  {
    const float b0 = bsum[k], b1 = bsum[32 + k], b2 = bsum[64 + k], b3 = bsum[96 + k];
    #pragma unroll
    for (int pi = 0; pi < 2; ++pi) { a0[pi] = b0; a1[pi] = b1; a2[pi] = b2; a3[pi] = b3; }
  }
  #pragma unroll
  for (int m4 = 0; m4 < 4; ++m4) {           // embedding part
    float4 w0 = W0[m4], w1 = W1[m4], w2 = W2[m4], w3 = W3[m4];
    #pragma unroll
    for (int pi = 0; pi < 2; ++pi) {
      float4 xv = ((const float4*)s.u.E[p0 + pi])[m4];
      a0[pi] += xv.x * w0.x + xv.y * w0.y + xv.z * w0.z + xv.w * w0.w;
      a1[pi] += xv.x * w1.x + xv.y * w1.y + xv.z * w1.z + xv.w * w1.w;
      a2[pi] += xv.x * w2.x + xv.y * w2.y + xv.z * w2.z + xv.w * w2.w;
      a3[pi] += xv.x * w3.x + xv.y * w3.y + xv.z * w3.z + xv.w * w3.w;
    }
  }
  #pragma unroll
  for (int m4 = 0; m4 < 8; ++m4) {           // hidden part
    float4 w0 = W0[4 + m4], w1 = W1[4 + m4], w2 = W2[4 + m4], w3 = W3[4 + m4];
    #pragma unroll
    for (int pi = 0; pi < 2; ++pi) {
      float4 hv = ((const float4*)Hin[p0 + pi])[m4];
      a0[pi] += hv.x * w0.x + hv.y * w0.y + hv.z * w0.z + hv.w * w0.w;
      a1[pi] += hv.x * w1.x + hv.y * w1.y + hv.z * w1.z + hv.w * w1.w;
      a2[pi] += hv.x * w2.x + hv.y * w2.y + hv.z * w2.z + hv.w * w2.w;
      a3[pi] += hv.x * w3.x + hv.y * w3.y + hv.z * w3.z + hv.w * w3.w;
    }
  }
  #pragma unroll
  for (int pi = 0; pi < 2; ++pi) {
    const int p = p0 + pi;
    float iv = sigm(a0[pi]), fv = sigm(a1[pi]);
    float gv = ftanh(a2[pi]), ov = sigm(a3[pi]);
    float cn = fv * s.C[p][k] + iv * gv;
    s.C[p][k] = cn;
    s.HC[p][k] = ov * ftanh(cn);
  }
}

__global__ __launch_bounds__(BDIM)
__attribute__((amdgpu_waves_per_eu(4, 4)))   // pin allocator target: 4 waves/EU -> 128-VGPR budget
void traj_fwd(
    const float* __restrict__ gx, const float* __restrict__ gdmat,
    const float* __restrict__ gbmat, const float* __restrict__ ghmat,
    const float* __restrict__ gimask,
    const float* __restrict__ gmean, const float* __restrict__ gvar,
    const float* __restrict__ gWemb, const float* __restrict__ gbemb,
    const float* __restrict__ gWihE, const float* __restrict__ gWhhE,
    const float* __restrict__ gbihE, const float* __restrict__ gbhhE,
    const float* __restrict__ gWihD, const float* __restrict__ gWhhD,
    const float* __restrict__ gbihD, const float* __restrict__ gbhhD,
    const float* __restrict__ gdom, const float* __restrict__ gWtemp,
    const float* __restrict__ gbtemp, const float* __restrict__ gWout,
    const float* __restrict__ gbout, float* __restrict__ gout)
{
  __shared__ Smem s;
  const int b = blockIdx.x, tid = threadIdx.x;

  // ---- stage constants; zero state; stage encoder LSTM weights ----
  for (int i = tid; i < 128; i += BDIM) {
    s.BsumE[i] = gbihE[i] + gbhhE[i];
    s.BsumD[i] = gbihD[i] + gbhhD[i];
  }
  for (int i = tid; i < 2048; i += BDIM) {
    int kp = i >> 6, m = i & 63;
    s.WtT[m][kp] = __float2bfloat16(gWtemp[i]);
  }
  for (int i = tid; i < 144; i += BDIM) s.Dom[i] = gdom[i];
  if (tid < 32) s.Btemp[tid] = gbtemp[tid];
  if (tid < 64) s.Wout[tid >> 5][tid & 31] = gWout[tid];
  if (tid < 2)  s.Bout[tid] = gbout[tid];
  if (tid < 16) s.Bemb[tid] = gbemb[tid];
  if (tid < 32) s.Wemb[tid >> 1][tid & 1] = gWemb[tid];
  if (tid < 4)  s.MV[tid] = (tid < 2) ? gmean[b * 2 + tid] : gvar[b * 2 + tid - 2];
  for (int i = tid; i < 2048; i += BDIM) { s.H[i >> 5][i & 31] = 0.0f; s.C[i >> 5][i & 31] = 0.0f; }
  stage_wl(tid, s, gWihE, gWhhE);
  __syncthreads();

  // Uniform-domain fast path detect (exact math shortcut: domain[ih,ib] == Dom[0]).
  bool uni = true;
  {
    const float d0 = s.Dom[0];
    for (int i = 0; i < 144; ++i) uni = uni && (s.Dom[i] == d0);
  }
  const float dom0 = s.Dom[0];

  // ================= ENCODER =================
  for (int t = 0; t < 8; ++t) {
    if (tid < 64) s.Mask[tid] = gimask[(b * 64 + tid) * 8 + t];
    if (tid < 128) {
      int p = tid >> 1, f = tid & 1;
      s.Xprev[p][f] = gx[((b * 64 + p) * 8 + t) * 2 + f];
    }
    __syncthreads();
    {  // W-build (+rowsum via shuffle) and E-build, fused phase
      const int i = tid >> 4, g = tid & 15, j4 = g * 4;
      const float mi = s.Mask[i];
      float w0, w1, w2, w3;
      if (uni) {
        const float4 dv = *(const float4*)&gdmat[(((b * 64 + i) * 8 + t) << 6) + j4];
        w0 = fmaxf(dom0 - dv.x, 0.0f) * mi * s.Mask[j4 + 0];
        w1 = fmaxf(dom0 - dv.y, 0.0f) * mi * s.Mask[j4 + 1];
        w2 = fmaxf(dom0 - dv.z, 0.0f) * mi * s.Mask[j4 + 2];
        w3 = fmaxf(dom0 - dv.w, 0.0f) * mi * s.Mask[j4 + 3];
      } else {
        float wq[4];
        #pragma unroll
        for (int c = 0; c < 4; ++c) {
          int gi = (((b * 64 + i) * 8 + t) << 6) + j4 + c;
          float dv = gdmat[gi], bv = gbmat[gi], hv = ghmat[gi];
          int ibn = (int)floorf(bv * (1.0f / 30.0f)); ibn = ibn < 0 ? 0 : (ibn > 11 ? 11 : ibn);
          int ihn = (int)floorf(hv * (1.0f / 30.0f)); ihn = ihn < 0 ? 0 : (ihn > 11 ? 11 : ihn);
          wq[c] = fmaxf(s.Dom[ihn * 12 + ibn] - dv, 0.0f) * mi * s.Mask[j4 + c];
        }
        w0 = wq[0]; w1 = wq[1]; w2 = wq[2]; w3 = wq[3];
      }
      *(float4*)&s.W[i][j4] = make_float4(w0, w1, w2, w3);
      float tot = w0 + w1 + w2 + w3;
      tot += __shfl_xor(tot, 1); tot += __shfl_xor(tot, 2);
      tot += __shfl_xor(tot, 4); tot += __shfl_xor(tot, 8);
      if (g == 0) s.RS[i] = 1.0f / (tot + 1e-8f);
      // E-build: one element per thread (p=i, k2=g)
      s.u.E[i][g] = s.Xprev[i][0] * s.Wemb[g][0] + s.Xprev[i][1] * s.Wemb[g][1] + s.Bemb[g];
    }
    __syncthreads();
    lstm_stream(tid, s, s.H, s.BsumE);
    __syncthreads();
    {  // spatial attention + tanh -> carry h and Enc[t]
      const int k2 = tid & 31, ig = tid >> 5;
      const int i0 = ig * 2, i1 = i0 + 1;
      float acc0 = 0.0f, acc1 = 0.0f;
      #pragma unroll
      for (int c = 0; c < 16; ++c) {
        float4 wv0 = *(const float4*)&s.W[i0][c * 4];
        float4 wv1 = *(const float4*)&s.W[i1][c * 4];
        float h0 = s.HC[c * 4 + 0][k2], h1 = s.HC[c * 4 + 1][k2];
        float h2 = s.HC[c * 4 + 2][k2], h3 = s.HC[c * 4 + 3][k2];
        acc0 += wv0.x * h0 + wv0.y * h1 + wv0.z * h2 + wv0.w * h3;
        acc1 += wv1.x * h0 + wv1.y * h1 + wv1.z * h2 + wv1.w * h3;
      }
      float v0 = ftanh(acc0 * s.RS[i0]);
      float v1 = ftanh(acc1 * s.RS[i1]);
      s.H[i0][k2] = v0; s.Enc[t][i0 * 33 + k2] = v0;
      s.H[i1][k2] = v1; s.Enc[t][i1 * 33 + k2] = v1;
    }
    __syncthreads();
  }

  // ================= DECODER =================
  stage_wl(tid, s, gWihD, gWhhD);
  for (int i = tid; i < 2048; i += BDIM) s.C[i >> 5][i & 31] = 0.0f;
  if (tid < 128) {
    int p = tid >> 1, f = tid & 1;
    s.Xprev[p][f] = gx[((b * 64 + p) * 8 + 7) * 2 + f];
  }
  if (tid < 64) s.Mask[tid] = gimask[(b * 64 + tid) * 8 + 7];
  __syncthreads();
  // W/RS for decoder step 0 == encoder t=7 (still resident)

  for (int sd = 0; sd < 12; ++sd) {
    {  // phase A: E-build + spatial attn on carry h -> Emb
      const int i = tid >> 4, g = tid & 15;
      s.u.E[i][g] = s.Xprev[i][0] * s.Wemb[g][0] + s.Xprev[i][1] * s.Wemb[g][1] + s.Bemb[g];
      const int k2 = tid & 31, ig = tid >> 5;
      const int i0 = ig * 2, i1 = i0 + 1;
      float acc0 = 0.0f, acc1 = 0.0f;
      #pragma unroll
      for (int c = 0; c < 16; ++c) {
        float4 wv0 = *(const float4*)&s.W[i0][c * 4];
        float4 wv1 = *(const float4*)&s.W[i1][c * 4];
        float h0 = s.H[c * 4 + 0][k2], h1 = s.H[c * 4 + 1][k2];
        float h2 = s.H[c * 4 + 2][k2], h3 = s.H[c * 4 + 3][k2];
        acc0 += wv0.x * h0 + wv0.y * h1 + wv0.z * h2 + wv0.w * h3;
        acc1 += wv1.x * h0 + wv1.y * h1 + wv1.z * h2 + wv1.w * h3;
      }
      s.Emb[i0][k2] = ftanh(acc0 * s.RS[i0]);
      s.Emb[i1][k2] = ftanh(acc1 * s.RS[i1]);
    }
    __syncthreads();
    lstm_stream(tid, s, s.Emb, s.BsumD);
    __syncthreads();
    {  // temporal attention: thread = (p = tid>>4, t = (tid>>1)&7, h = tid&1)
      const int p = tid >> 4, t8 = (tid >> 1) & 7, h = tid & 1;
      const float* hcr = &s.HC[p][h * 16];
      const float* enr = &s.Enc[t8][p * 33 + h * 16];
      float sc = 0.0f;
      #pragma unroll
      for (int kk = 0; kk < 16; ++kk) sc += hcr[kk] * enr[kk];
      sc += __shfl_xor(sc, 1);
      sc *= 0.17677669529663687f;   // 1/sqrt(32)
      float m = gimask[(b * 64 + p) * 8 + t8];
      sc = (m > 0.0f) ? sc : -1e9f;
      float mx = sc;
      mx = fmaxf(mx, __shfl_xor(mx, 2));
      mx = fmaxf(mx, __shfl_xor(mx, 4));
      mx = fmaxf(mx, __shfl_xor(mx, 8));
      float e = __expf(sc - mx);
      float den = e;
      den += __shfl_xor(den, 2);
      den += __shfl_xor(den, 4);
      den += __shfl_xor(den, 8);
      float a = e / den;
      const int kb = t8 * 4 + h * 2;
      float c0 = 0.0f, c1 = 0.0f;
      #pragma unroll
      for (int tt = 0; tt < 8; ++tt) {
        float av = __shfl(a, tt * 2, 16);
        const float* er = &s.Enc[tt][p * 33 + kb];
        c0 += av * er[0]; c1 += av * er[1];
      }
      s.u.Ctx[p][kb] = c0; s.u.Ctx[p][kb + 1] = c1;
    }
    __syncthreads();
    {  // wtemp (+ fused x_out via half-wave shuffle reduce)
      const int kp = tid & 31, pg = tid >> 5;
      float r00, r01, r10, r11;
      #pragma unroll
      for (int pi = 0; pi < 2; ++pi) {
        const int p = pg * 2 + pi;
        float a = s.Btemp[kp];
        #pragma unroll
        for (int m = 0; m < 32; ++m) a += s.u.Ctx[p][m] * __bfloat162float(s.WtT[m][kp]);
        #pragma unroll
        for (int m = 0; m < 32; ++m) a += s.HC[p][m] * __bfloat162float(s.WtT[32 + m][kp]);
        float hv = ftanh(a);
        s.H[p][kp] = hv;
        if (pi == 0) { r00 = hv * s.Wout[0][kp]; r01 = hv * s.Wout[1][kp]; }
        else         { r10 = hv * s.Wout[0][kp]; r11 = hv * s.Wout[1][kp]; }
      }
      #pragma unroll
      for (int st = 1; st < 32; st <<= 1) {
        r00 += __shfl_xor(r00, st); r01 += __shfl_xor(r01, st);
        r10 += __shfl_xor(r10, st); r11 += __shfl_xor(r11, st);
      }
      if (kp == 0) {
        const int p0 = pg * 2;
        float v00 = ftanh(r00 + s.Bout[0]);
        float v01 = ftanh(r01 + s.Bout[1]);
        float v10 = ftanh(r10 + s.Bout[0]);
        float v11 = ftanh(r11 + s.Bout[1]);
        s.Xout[p0][0] = v00; s.Xout[p0][1] = v01;
        s.Xout[p0 + 1][0] = v10; s.Xout[p0 + 1][1] = v11;
        float* go = &gout[((b * 64 + p0) * 12 + sd) * 2];
        go[0] = v00; go[1] = v01; go[24] = v10; go[25] = v11;
      }
    }
    __syncthreads();
    if (sd < 11) {
      if (uni) {
        // fast path: dist depends only on Xout diffs; heading dead.
        const int i = tid >> 4, g = tid & 15, j4 = g * 4;
        const float v0 = s.MV[2], v1 = s.MV[3];
        const float xi0 = s.Xout[i][0], xi1 = s.Xout[i][1];
        const float mi = s.Mask[i];
        float wq[4];
        #pragma unroll
        for (int c = 0; c < 4; ++c) {
          const int j = j4 + c;
          float rx = (s.Xout[j][0] - xi0) * v0;
          float ry = (s.Xout[j][1] - xi1) * v1;
          float dist = sqrtf(rx * rx + ry * ry + 1e-12f);
          wq[c] = fmaxf(dom0 - dist, 0.0f) * mi * s.Mask[j];
        }
        *(float4*)&s.W[i][j4] = make_float4(wq[0], wq[1], wq[2], wq[3]);
        float tot = wq[0] + wq[1] + wq[2] + wq[3];
        tot += __shfl_xor(tot, 1); tot += __shfl_xor(tot, 2);
        tot += __shfl_xor(tot, 4); tot += __shfl_xor(tot, 8);
        if (g == 0) s.RS[i] = 1.0f / (tot + 1e-8f);
        if (tid < 128) { int p = tid >> 1, f = tid & 1; s.Xprev[p][f] = s.Xout[p][f]; }
      } else {
        if (tid < 64) {
          const int p = tid;
          float m0 = s.MV[0], m1 = s.MV[1], v0 = s.MV[2], v1 = s.MV[3];
          float px = s.Xout[p][0] * v0 + m0, py = s.Xout[p][1] * v1 + m1;
          float qx = s.Xprev[p][0] * v0 + m0, qy = s.Xprev[p][1] * v1 + m1;
          s.Head[p] = mod360(atan2_deg(py - qy, px - qx));
          s.Pos[p][0] = px; s.Pos[p][1] = py;
        }
        __syncthreads();
        const int i = tid >> 4, g = tid & 15, j4 = g * 4;
        const float mi = s.Mask[i], hi = s.Head[i];
        const float pix = s.Pos[i][0], piy = s.Pos[i][1];
        float wq[4];
        #pragma unroll
        for (int c = 0; c < 4; ++c) {
          const int j = j4 + c;
          float rx = s.Pos[j][0] - pix;
          float ry = s.Pos[j][1] - piy;
          float dist = sqrtf(rx * rx + ry * ry + 1e-12f);
          float rb = mod360(atan2_deg(ry, rx) - hi);
          float rh = mod360(s.Head[j] - hi);
          int ibn = (int)floorf(rb * (1.0f / 30.0f)); ibn = ibn < 0 ? 0 : (ibn > 11 ? 11 : ibn);
          int ihn = (int)floorf(rh * (1.0f / 30.0f)); ihn = ihn < 0 ? 0 : (ihn > 11 ? 11 : ihn);
          wq[c] = fmaxf(s.Dom[ihn * 12 + ibn] - dist, 0.0f) * mi * s.Mask[j];
        }
        *(float4*)&s.W[i][j4] = make_float4(wq[0], wq[1], wq[2], wq[3]);
        float tot = wq[0] + wq[1] + wq[2] + wq[3];
        tot += __shfl_xor(tot, 1); tot += __shfl_xor(tot, 2);
        tot += __shfl_xor(tot, 4); tot += __shfl_xor(tot, 8);
        if (g == 0) s.RS[i] = 1.0f / (tot + 1e-8f);
        if (tid < 128) { int p = tid >> 1, f = tid & 1; s.Xprev[p][f] = s.Xout[p][f]; }
      }
      __syncthreads();
    }
  }
}

extern "C" void kernel_launch(void* const* d_in, const int* in_sizes, int n_in,
                              void* d_out, int out_size, void* d_ws, size_t ws_size,
                              hipStream_t stream) {
  (void)in_sizes; (void)n_in; (void)d_ws; (void)ws_size; (void)out_size;
  traj_fwd<<<512, BDIM, 0, stream>>>(
      (const float*)d_in[0], (const float*)d_in[1], (const float*)d_in[2],
      (const float*)d_in[3], (const float*)d_in[4],
      /* d_in[5] output_mask, d_in[6] scene unused */
      (const float*)d_in[7], (const float*)d_in[8],
      (const float*)d_in[9], (const float*)d_in[10],
      (const float*)d_in[11], (const float*)d_in[12],
      (const float*)d_in[13], (const float*)d_in[14],
      (const float*)d_in[15], (const float*)d_in[16],
      (const float*)d_in[17], (const float*)d_in[18],
      (const float*)d_in[19], (const float*)d_in[20],
      (const float*)d_in[21], (const float*)d_in[22], (const float*)d_in[23],
      (float*)d_out);
}

// Round 7
// 614.693 us; speedup vs baseline: 1.1184x; 1.1165x over previous
//
#include <hip/hip_runtime.h>
#include <hip/hip_bf16.h>
#include <math.h>

#define BDIM 512
typedef __hip_bfloat16 bf16;

// Device buffers confirmed float32.
// NOTE (r4-r6): BDIM=1024 forces a 64-VGPR budget on this toolchain (launch_bounds
// and amdgpu_waves_per_eu both ignored) -> massive scratch spills. BDIM=512 with
// __launch_bounds__(512,2) is the proven 128-VGPR spill-free config (r3).

__device__ __forceinline__ float sigm(float v)  { return 1.0f / (1.0f + __expf(-v)); }
// tanh via hardware exp: exact at saturation, ~1e-6 abs err elsewhere.
__device__ __forceinline__ float ftanh(float v) { return 1.0f - 2.0f / (__expf(2.0f * v) + 1.0f); }
__device__ __forceinline__ float mod360(float v){ return v - 360.0f * floorf(v * (1.0f / 360.0f)); }

// atan2 in degrees (slow path only; result feeds 30-deg bins).
__device__ __forceinline__ float atan2_deg(float y, float x) {
  float ax = fabsf(x), ay = fabsf(y);
  float mx = fmaxf(ax, ay), mn = fminf(ax, ay);
  float r = mn / fmaxf(mx, 1e-30f);
  float r2 = r * r;
  float a = r * (0.99997726f + r2 * (-0.33262347f + r2 * (0.19354346f +
            r2 * (-0.11643287f + r2 * (0.05265332f - r2 * 0.01172120f)))));
  if (ay > ax) a = 1.5707963267948966f - a;
  if (x < 0.0f) a = 3.141592653589793f - a;
  a = copysignf(a, y);
  return a * 57.29577951308232f;
}

union EUCtx {
  float E[64][16];    // embedding (live: step start -> LSTM)
  float Ctx[64][33];  // temporal context (live: temporal -> wtemp)
};

struct Smem {
  alignas(16) float H[64][32];     // carry h
  alignas(16) float C[64][32];     // carry c
  float HC[64][33];                // lstm output (pad 33)
  alignas(16) float Emb[64][32];   // decoder spatial output
  alignas(16) EUCtx u;
  float Enc[8][2120];              // [t][p*33+k]
  alignas(16) float W[64][68];     // spatial weights (stride 68: float4-aligned)
  float RS[64];                    // 1/(rowsum+1e-8)
  bf16  WtT[64][32];               // W_temp^T, bf16
  alignas(16) float WL[128][52];   // LSTM weights [j][ih(16)|hh(32)|pad]
  float Wemb[16][2];
  float Bemb[16];
  float BsumE[128], BsumD[128];
  float Dom[144];
  float Btemp[32];
  float Wout[2][32];
  float Bout[2];
  float Mask[64];
  float Pos[64][2];                // slow path only
  float Head[64];                  // slow path only
  float Xprev[64][2];
  float Xout[64][2];
  float MV[4];
};
static_assert(sizeof(Smem) <= 160 * 1024, "LDS over budget");

__device__ __forceinline__ void stage_wl(int tid, Smem& s,
    const float* __restrict__ Wih, const float* __restrict__ Whh) {
  for (int idx = tid; idx < 128 * 48; idx += BDIM) {
    int j = idx / 48, m = idx - j * 48;
    s.WL[j][m] = (m < 16) ? Wih[j * 16 + m] : Whh[j * 32 + (m - 16)];
  }
}

// LSTM: thread (k=tid&31, pg=tid>>5) -> 4 gates x 4 pedestrians (r3-proven shape).
__device__ __forceinline__ void lstm_stream(int tid, Smem& s,
    const float (*Hin)[32], const float* __restrict__ bsum) {
  const int k = tid & 31, pg = tid >> 5, p0 = pg * 4;
  const float4* W0 = (const float4*)s.WL[k];
  const float4* W1 = (const float4*)s.WL[32 + k];
  const float4* W2 = (const float4*)s.WL[64 + k];
  const float4* W3 = (const float4*)s.WL[96 + k];
  float a0[4], a1[4], a2[4], a3[4];
  {
    const float b0 = bsum[k], b1 = bsum[32 + k], b2 = bsum[64 + k], b3 = bsum[96 + k];
    #pragma unroll
    for (int pi = 0; pi < 4; ++pi) { a0[pi] = b0; a1[pi] = b1; a2[pi] = b2; a3[pi] = b3; }
  }
  #pragma unroll
  for (int m4 = 0; m4 < 4; ++m4) {           // embedding part
    float4 w0 = W0[m4], w1 = W1[m4], w2 = W2[m4], w3 = W3[m4];
    #pragma unroll
    for (int pi = 0; pi < 4; ++pi) {
      float4 xv = ((const float4*)s.u.E[p0 + pi])[m4];
      a0[pi] += xv.x * w0.x + xv.y * w0.y + xv.z * w0.z + xv.w * w0.w;
      a1[pi] += xv.x * w1.x + xv.y * w1.y + xv.z * w1.z + xv.w * w1.w;
      a2[pi] += xv.x * w2.x + xv.y * w2.y + xv.z * w2.z + xv.w * w2.w;
      a3[pi] += xv.x * w3.x + xv.y * w3.y + xv.z * w3.z + xv.w * w3.w;
    }
  }
  #pragma unroll
  for (int m4 = 0; m4 < 8; ++m4) {           // hidden part
    float4 w0 = W0[4 + m4], w1 = W1[4 + m4], w2 = W2[4 + m4], w3 = W3[4 + m4];
    #pragma unroll
    for (int pi = 0; pi < 4; ++pi) {
      float4 hv = ((const float4*)Hin[p0 + pi])[m4];
      a0[pi] += hv.x * w0.x + hv.y * w0.y + hv.z * w0.z + hv.w * w0.w;
      a1[pi] += hv.x * w1.x + hv.y * w1.y + hv.z * w1.z + hv.w * w1.w;
      a2[pi] += hv.x * w2.x + hv.y * w2.y + hv.z * w2.z + hv.w * w2.w;
      a3[pi] += hv.x * w3.x + hv.y * w3.y + hv.z * w3.z + hv.w * w3.w;
    }
  }
  #pragma unroll
  for (int pi = 0; pi < 4; ++pi) {
    const int p = p0 + pi;
    float iv = sigm(a0[pi]), fv = sigm(a1[pi]);
    float gv = ftanh(a2[pi]), ov = sigm(a3[pi]);
    float cn = fv * s.C[p][k] + iv * gv;
    s.C[p][k] = cn;
    s.HC[p][k] = ov * ftanh(cn);
  }
}

__global__ __launch_bounds__(BDIM, 2) void traj_fwd(
    const float* __restrict__ gx, const float* __restrict__ gdmat,
    const float* __restrict__ gbmat, const float* __restrict__ ghmat,
    const float* __restrict__ gimask,
    const float* __restrict__ gmean, const float* __restrict__ gvar,
    const float* __restrict__ gWemb, const float* __restrict__ gbemb,
    const float* __restrict__ gWihE, const float* __restrict__ gWhhE,
    const float* __restrict__ gbihE, const float* __restrict__ gbhhE,
    const float* __restrict__ gWihD, const float* __restrict__ gWhhD,
    const float* __restrict__ gbihD, const float* __restrict__ gbhhD,
    const float* __restrict__ gdom, const float* __restrict__ gWtemp,
    const float* __restrict__ gbtemp, const float* __restrict__ gWout,
    const float* __restrict__ gbout, float* __restrict__ gout)
{
  __shared__ Smem s;
  const int b = blockIdx.x, tid = threadIdx.x;

  // ---- stage constants; zero state; stage encoder LSTM weights ----
  for (int i = tid; i < 128; i += BDIM) {
    s.BsumE[i] = gbihE[i] + gbhhE[i];
    s.BsumD[i] = gbihD[i] + gbhhD[i];
  }
  for (int i = tid; i < 2048; i += BDIM) {
    int kp = i >> 6, m = i & 63;
    s.WtT[m][kp] = __float2bfloat16(gWtemp[i]);
  }
  for (int i = tid; i < 144; i += BDIM) s.Dom[i] = gdom[i];
  if (tid < 32) s.Btemp[tid] = gbtemp[tid];
  if (tid < 64) s.Wout[tid >> 5][tid & 31] = gWout[tid];
  if (tid < 2)  s.Bout[tid] = gbout[tid];
  if (tid < 16) s.Bemb[tid] = gbemb[tid];
  if (tid < 32) s.Wemb[tid >> 1][tid & 1] = gWemb[tid];
  if (tid < 4)  s.MV[tid] = (tid < 2) ? gmean[b * 2 + tid] : gvar[b * 2 + tid - 2];
  for (int i = tid; i < 2048; i += BDIM) { s.H[i >> 5][i & 31] = 0.0f; s.C[i >> 5][i & 31] = 0.0f; }
  stage_wl(tid, s, gWihE, gWhhE);
  __syncthreads();

  // Uniform-domain fast path detect (exact math shortcut: domain[ih,ib] == Dom[0]).
  bool uni = true;
  {
    const float d0 = s.Dom[0];
    for (int i = 0; i < 144; ++i) uni = uni && (s.Dom[i] == d0);
  }
  const float dom0 = s.Dom[0];

  // ================= ENCODER =================
  for (int t = 0; t < 8; ++t) {
    if (tid < 64) s.Mask[tid] = gimask[(b * 64 + tid) * 8 + t];
    if (tid < 128) {
      int p = tid >> 1, f = tid & 1;
      s.Xprev[p][f] = gx[((b * 64 + p) * 8 + t) * 2 + f];
    }
    __syncthreads();
    {  // W-build (8 cols/thread) + rowsum via 8-lane shuffle + E-build
      const int i = tid >> 3, g = tid & 7, j8 = g * 8;
      const float mi = s.Mask[i];
      const int gbase = (((b * 64 + i) * 8 + t) << 6) + j8;
      float w[8];
      if (uni) {
        const float4 dv0 = *(const float4*)&gdmat[gbase];
        const float4 dv1 = *(const float4*)&gdmat[gbase + 4];
        w[0] = fmaxf(dom0 - dv0.x, 0.0f) * mi * s.Mask[j8 + 0];
        w[1] = fmaxf(dom0 - dv0.y, 0.0f) * mi * s.Mask[j8 + 1];
        w[2] = fmaxf(dom0 - dv0.z, 0.0f) * mi * s.Mask[j8 + 2];
        w[3] = fmaxf(dom0 - dv0.w, 0.0f) * mi * s.Mask[j8 + 3];
        w[4] = fmaxf(dom0 - dv1.x, 0.0f) * mi * s.Mask[j8 + 4];
        w[5] = fmaxf(dom0 - dv1.y, 0.0f) * mi * s.Mask[j8 + 5];
        w[6] = fmaxf(dom0 - dv1.z, 0.0f) * mi * s.Mask[j8 + 6];
        w[7] = fmaxf(dom0 - dv1.w, 0.0f) * mi * s.Mask[j8 + 7];
      } else {
        #pragma unroll
        for (int c = 0; c < 8; ++c) {
          int gi = gbase + c;
          float dv = gdmat[gi], bv = gbmat[gi], hv = ghmat[gi];
          int ibn = (int)floorf(bv * (1.0f / 30.0f)); ibn = ibn < 0 ? 0 : (ibn > 11 ? 11 : ibn);
          int ihn = (int)floorf(hv * (1.0f / 30.0f)); ihn = ihn < 0 ? 0 : (ihn > 11 ? 11 : ihn);
          w[c] = fmaxf(s.Dom[ihn * 12 + ibn] - dv, 0.0f) * mi * s.Mask[j8 + c];
        }
      }
      *(float4*)&s.W[i][j8]     = make_float4(w[0], w[1], w[2], w[3]);
      *(float4*)&s.W[i][j8 + 4] = make_float4(w[4], w[5], w[6], w[7]);
      float tot = ((w[0] + w[1]) + (w[2] + w[3])) + ((w[4] + w[5]) + (w[6] + w[7]));
      tot += __shfl_xor(tot, 1); tot += __shfl_xor(tot, 2); tot += __shfl_xor(tot, 4);
      if (g == 0) s.RS[i] = 1.0f / (tot + 1e-8f);
      // E-build: 2 elems/thread
      {
        const int p = tid >> 3, k2a = (tid & 7) * 2;
        s.u.E[p][k2a]     = s.Xprev[p][0] * s.Wemb[k2a][0]     + s.Xprev[p][1] * s.Wemb[k2a][1]     + s.Bemb[k2a];
        s.u.E[p][k2a + 1] = s.Xprev[p][0] * s.Wemb[k2a + 1][0] + s.Xprev[p][1] * s.Wemb[k2a + 1][1] + s.Bemb[k2a + 1];
      }
    }
    __syncthreads();
    lstm_stream(tid, s, s.H, s.BsumE);
    __syncthreads();
    {  // spatial attention + tanh -> carry h and Enc[t] (4 rows/thread)
      const int k2 = tid & 31, ig = tid >> 5, i0 = ig * 4;
      float acc[4] = {};
      #pragma unroll
      for (int c = 0; c < 16; ++c) {
        float h0 = s.HC[c * 4 + 0][k2], h1 = s.HC[c * 4 + 1][k2];
        float h2 = s.HC[c * 4 + 2][k2], h3 = s.HC[c * 4 + 3][k2];
        #pragma unroll
        for (int ii = 0; ii < 4; ++ii) {
          float4 wv = *(const float4*)&s.W[i0 + ii][c * 4];
          acc[ii] += wv.x * h0 + wv.y * h1 + wv.z * h2 + wv.w * h3;
        }
      }
      #pragma unroll
      for (int ii = 0; ii < 4; ++ii) {
        int i = i0 + ii;
        float v = ftanh(acc[ii] * s.RS[i]);
        s.H[i][k2] = v;
        s.Enc[t][i * 33 + k2] = v;
      }
    }
    __syncthreads();
  }

  // ================= DECODER =================
  stage_wl(tid, s, gWihD, gWhhD);
  for (int i = tid; i < 2048; i += BDIM) s.C[i >> 5][i & 31] = 0.0f;
  if (tid < 128) {
    int p = tid >> 1, f = tid & 1;
    s.Xprev[p][f] = gx[((b * 64 + p) * 8 + 7) * 2 + f];
  }
  if (tid < 64) s.Mask[tid] = gimask[(b * 64 + tid) * 8 + 7];
  __syncthreads();
  // W/RS for decoder step 0 == encoder t=7 (still resident)

  for (int sd = 0; sd < 12; ++sd) {
    {  // phase A: E-build + spatial attn on carry h -> Emb
      {
        const int p = tid >> 3, k2a = (tid & 7) * 2;
        s.u.E[p][k2a]     = s.Xprev[p][0] * s.Wemb[k2a][0]     + s.Xprev[p][1] * s.Wemb[k2a][1]     + s.Bemb[k2a];
        s.u.E[p][k2a + 1] = s.Xprev[p][0] * s.Wemb[k2a + 1][0] + s.Xprev[p][1] * s.Wemb[k2a + 1][1] + s.Bemb[k2a + 1];
      }
      const int k2 = tid & 31, ig = tid >> 5, i0 = ig * 4;
      float acc[4] = {};
      #pragma unroll
      for (int c = 0; c < 16; ++c) {
        float h0 = s.H[c * 4 + 0][k2], h1 = s.H[c * 4 + 1][k2];
        float h2 = s.H[c * 4 + 2][k2], h3 = s.H[c * 4 + 3][k2];
        #pragma unroll
        for (int ii = 0; ii < 4; ++ii) {
          float4 wv = *(const float4*)&s.W[i0 + ii][c * 4];
          acc[ii] += wv.x * h0 + wv.y * h1 + wv.z * h2 + wv.w * h3;
        }
      }
      #pragma unroll
      for (int ii = 0; ii < 4; ++ii)
        s.Emb[i0 + ii][k2] = ftanh(acc[ii] * s.RS[i0 + ii]);
    }
    __syncthreads();
    lstm_stream(tid, s, s.Emb, s.BsumD);
    __syncthreads();
    {  // temporal attention: thread = (p = tid>>3, t = tid&7)
      const int p = tid >> 3, t8 = tid & 7;
      const float* hcr = s.HC[p];
      const float* enr = &s.Enc[t8][p * 33];
      float sc = 0.0f;
      #pragma unroll
      for (int k2 = 0; k2 < 32; ++k2) sc += hcr[k2] * enr[k2];
      sc *= 0.17677669529663687f;   // 1/sqrt(32)
      float m = gimask[(b * 64 + p) * 8 + t8];
      sc = (m > 0.0f) ? sc : -1e9f;
      float mx = sc;
      mx = fmaxf(mx, __shfl_xor(mx, 1));
      mx = fmaxf(mx, __shfl_xor(mx, 2));
      mx = fmaxf(mx, __shfl_xor(mx, 4));
      float e = __expf(sc - mx);
      float den = e;
      den += __shfl_xor(den, 1);
      den += __shfl_xor(den, 2);
      den += __shfl_xor(den, 4);
      float a = e / den;
      float av[8];
      #pragma unroll
      for (int tt = 0; tt < 8; ++tt) av[tt] = __shfl(a, tt, 8);
      const int kb = t8 * 4;
      float c0 = 0, c1 = 0, c2 = 0, c3 = 0;
      #pragma unroll
      for (int tt = 0; tt < 8; ++tt) {
        const float* er = &s.Enc[tt][p * 33 + kb];
        c0 += av[tt] * er[0]; c1 += av[tt] * er[1];
        c2 += av[tt] * er[2]; c3 += av[tt] * er[3];
      }
      s.u.Ctx[p][kb] = c0; s.u.Ctx[p][kb + 1] = c1;
      s.u.Ctx[p][kb + 2] = c2; s.u.Ctx[p][kb + 3] = c3;
    }
    __syncthreads();
    {  // wtemp (+ fused x_out via 32-lane shuffle reduce), 4 peds/thread-group
      const int kp = tid & 31, pg = tid >> 5;
      float r0[4], r1[4];
      #pragma unroll
      for (int pi = 0; pi < 4; ++pi) {
        const int p = pg * 4 + pi;
        float a = s.Btemp[kp];
        #pragma unroll
        for (int m = 0; m < 32; ++m) a += s.u.Ctx[p][m] * __bfloat162float(s.WtT[m][kp]);
        #pragma unroll
        for (int m = 0; m < 32; ++m) a += s.HC[p][m] * __bfloat162float(s.WtT[32 + m][kp]);
        float hv = ftanh(a);
        s.H[p][kp] = hv;
        r0[pi] = hv * s.Wout[0][kp];
        r1[pi] = hv * s.Wout[1][kp];
      }
      #pragma unroll
      for (int st = 1; st < 32; st <<= 1) {
        #pragma unroll
        for (int pi = 0; pi < 4; ++pi) {
          r0[pi] += __shfl_xor(r0[pi], st);
          r1[pi] += __shfl_xor(r1[pi], st);
        }
      }
      if (kp == 0) {
        const int p0 = pg * 4;
        float* go = &gout[((b * 64 + p0) * 12 + sd) * 2];
        #pragma unroll
        for (int pi = 0; pi < 4; ++pi) {
          float vx = ftanh(r0[pi] + s.Bout[0]);
          float vy = ftanh(r1[pi] + s.Bout[1]);
          s.Xout[p0 + pi][0] = vx; s.Xout[p0 + pi][1] = vy;
          go[pi * 24] = vx; go[pi * 24 + 1] = vy;
        }
      }
    }
    __syncthreads();
    if (sd < 11) {
      if (uni) {
        // fast path: dist from Xout diffs only; heading/atan2 dead.
        const int i = tid >> 3, g = tid & 7, j8 = g * 8;
        const float v0 = s.MV[2], v1 = s.MV[3];
        const float xi0 = s.Xout[i][0], xi1 = s.Xout[i][1];
        const float mi = s.Mask[i];
        float w[8];
        #pragma unroll
        for (int c = 0; c < 8; ++c) {
          const int j = j8 + c;
          float rx = (s.Xout[j][0] - xi0) * v0;
          float ry = (s.Xout[j][1] - xi1) * v1;
          float dist = sqrtf(rx * rx + ry * ry + 1e-12f);
          w[c] = fmaxf(dom0 - dist, 0.0f) * mi * s.Mask[j];
        }
        *(float4*)&s.W[i][j8]     = make_float4(w[0], w[1], w[2], w[3]);
        *(float4*)&s.W[i][j8 + 4] = make_float4(w[4], w[5], w[6], w[7]);
        float tot = ((w[0] + w[1]) + (w[2] + w[3])) + ((w[4] + w[5]) + (w[6] + w[7]));
        tot += __shfl_xor(tot, 1); tot += __shfl_xor(tot, 2); tot += __shfl_xor(tot, 4);
        if (g == 0) s.RS[i] = 1.0f / (tot + 1e-8f);
        if (tid < 128) { int p = tid >> 1, f = tid & 1; s.Xprev[p][f] = s.Xout[p][f]; }
      } else {
        if (tid < 64) {
          const int p = tid;
          float m0 = s.MV[0], m1 = s.MV[1], v0 = s.MV[2], v1 = s.MV[3];
          float px = s.Xout[p][0] * v0 + m0, py = s.Xout[p][1] * v1 + m1;
          float qx = s.Xprev[p][0] * v0 + m0, qy = s.Xprev[p][1] * v1 + m1;
          s.Head[p] = mod360(atan2_deg(py - qy, px - qx));
          s.Pos[p][0] = px; s.Pos[p][1] = py;
        }
        __syncthreads();
        const int i = tid >> 3, g = tid & 7, j8 = g * 8;
        const float mi = s.Mask[i], hi = s.Head[i];
        const float pix = s.Pos[i][0], piy = s.Pos[i][1];
        float w[8];
        #pragma unroll
        for (int c = 0; c < 8; ++c) {
          const int j = j8 + c;
          float rx = s.Pos[j][0] - pix;
          float ry = s.Pos[j][1] - piy;
          float dist = sqrtf(rx * rx + ry * ry + 1e-12f);
          float rb = mod360(atan2_deg(ry, rx) - hi);
          float rh = mod360(s.Head[j] - hi);
          int ibn = (int)floorf(rb * (1.0f / 30.0f)); ibn = ibn < 0 ? 0 : (ibn > 11 ? 11 : ibn);
          int ihn = (int)floorf(rh * (1.0f / 30.0f)); ihn = ihn < 0 ? 0 : (ihn > 11 ? 11 : ihn);
          w[c] = fmaxf(s.Dom[ihn * 12 + ibn] - dist, 0.0f) * mi * s.Mask[j];
        }
        *(float4*)&s.W[i][j8]     = make_float4(w[0], w[1], w[2], w[3]);
        *(float4*)&s.W[i][j8 + 4] = make_float4(w[4], w[5], w[6], w[7]);
        float tot = ((w[0] + w[1]) + (w[2] + w[3])) + ((w[4] + w[5]) + (w[6] + w[7]));
        tot += __shfl_xor(tot, 1); tot += __shfl_xor(tot, 2); tot += __shfl_xor(tot, 4);
        if (g == 0) s.RS[i] = 1.0f / (tot + 1e-8f);
        if (tid < 128) { int p = tid >> 1, f = tid & 1; s.Xprev[p][f] = s.Xout[p][f]; }
      }
      __syncthreads();
    }
  }
}

extern "C" void kernel_launch(void* const* d_in, const int* in_sizes, int n_in,
                              void* d_out, int out_size, void* d_ws, size_t ws_size,
                              hipStream_t stream) {
  (void)in_sizes; (void)n_in; (void)d_ws; (void)ws_size; (void)out_size;
  traj_fwd<<<512, BDIM, 0, stream>>>(
      (const float*)d_in[0], (const float*)d_in[1], (const float*)d_in[2],
      (const float*)d_in[3], (const float*)d_in[4],
      /* d_in[5] output_mask, d_in[6] scene unused */
      (const float*)d_in[7], (const float*)d_in[8],
      (const float*)d_in[9], (const float*)d_in[10],
      (const float*)d_in[11], (const float*)d_in[12],
      (const float*)d_in[13], (const float*)d_in[14],
      (const float*)d_in[15], (const float*)d_in[16],
      (const float*)d_in[17], (const float*)d_in[18],
      (const float*)d_in[19], (const float*)d_in[20],
      (const float*)d_in[21], (const float*)d_in[22], (const float*)d_in[23],
      (float*)d_out);
}